// Round 8
// baseline (381.212 us; speedup 1.0000x reference)
//
#include <hip/hip_runtime.h>
#include <cstddef>

// ============================================================================
// MaskedMultiHeadAttention (B=4,S=2048,DM=1024,H=16,HD=64), faithful to ref:
//   softmax over the QUERY axis (axis=2), then /sqrt(HD); mask is a no-op.
// Round 11 == Round 10 resubmit (round-10 bench failed on container infra;
// source audited for deadlock/OOB — none; workspace identical to passing r8/r9):
//   - gemm_bt: LDS double-buffer (64KB) + counted vmcnt(8) + raw s_barrier,
//     never vmcnt(0) mid-loop (attn r8's proven pattern). Kills the per-K-step
//     vmcnt(0) drain of the old single-buffer 2-barrier loop.
//   - cvt(q)+cvt(k) merged into one dispatch again (cvt2_kernel).
//   - attn (r9 pipeline), stats (r6 form), wt unchanged.
// ============================================================================

typedef unsigned short u16t;
typedef __attribute__((ext_vector_type(8))) short short8;
typedef __attribute__((ext_vector_type(4))) float floatx4;
typedef __attribute__((ext_vector_type(4))) unsigned int uintx4;

#define MFMA16(a, b, c) __builtin_amdgcn_mfma_f32_16x16x32_bf16((a), (b), (c), 0, 0, 0)
#define GLDS16(g, l)                                                        \
  __builtin_amdgcn_global_load_lds(                                         \
      (const __attribute__((address_space(1))) unsigned int*)(g),           \
      (__attribute__((address_space(3))) unsigned int*)(l), 16, 0, 0)

#if __has_builtin(__builtin_amdgcn_exp2f)
#define EXP2(x) __builtin_amdgcn_exp2f(x)
#else
#define EXP2(x) __expf(0.69314718f * (x))
#endif

static __device__ __forceinline__ u16t f2bf(float f) {
  union { float f; unsigned u; } v; v.f = f;
  unsigned r = v.u + 0x7FFFu + ((v.u >> 16) & 1u);  // RNE
  return (u16t)(r >> 16);
}
// Pack two f32 -> two bf16 (round-half-up) in one v_perm: hi<<16 | lo.
static __device__ __forceinline__ unsigned pack2(float hi, float lo) {
  union { float f; unsigned u; } a, b; a.f = hi; b.f = lo;
  return __builtin_amdgcn_perm(a.u + 0x8000u, b.u + 0x8000u, 0x07060302u);
}
// HW packed f32->bf16 (RNE): D = {hi16=cvt(hi), lo16=cvt(lo)} in one VALU op.
static __device__ __forceinline__ unsigned cvtpk(float lo, float hi) {
  unsigned r;
  asm("v_cvt_pk_bf16_f32 %0, %1, %2" : "=v"(r) : "v"(lo), "v"(hi));
  return r;
}

// XOR swizzle within a 64/128-elem row block: breaks 128B/256B bank period.
static __device__ __forceinline__ int swz(int row, int col) {
  return (((col >> 3) ^ (row & 7)) << 3) | (col & 7);
}

#define SEQ    2048
#define NHEAD  16
#define HDIM   64
#define DMODEL 1024

// ---------------------------------------------------------------------------
// All four W [1024][1024] f32 -> WT [n][k-swizzled] bf16 in one dispatch.
__global__ __launch_bounds__(256)
void wt_kernel(const float* __restrict__ W0, const float* __restrict__ W1,
               const float* __restrict__ W2, const float* __restrict__ W3,
               u16t* __restrict__ T0, u16t* __restrict__ T1,
               u16t* __restrict__ T2, u16t* __restrict__ T3) {
  int id = blockIdx.x * 256 + threadIdx.x;  // 2048 blocks -> 524288 ids
  int wsel = id >> 17;
  int r = id & 131071;
  int n = r & 1023;
  int k0 = (r >> 10) << 3;
  const float* W = wsel == 0 ? W0 : wsel == 1 ? W1 : wsel == 2 ? W2 : W3;
  u16t* T = wsel == 0 ? T0 : wsel == 1 ? T1 : wsel == 2 ? T2 : T3;
  const float* src = W + (size_t)k0 * 1024 + n;
  float f[8];
#pragma unroll
  for (int i = 0; i < 8; ++i) f[i] = src[(size_t)i * 1024];
  uint4 p;
  p.x = pack2(f[1], f[0]); p.y = pack2(f[3], f[2]);
  p.z = pack2(f[5], f[4]); p.w = pack2(f[7], f[6]);
  *(uint4*)&T[(size_t)n * 1024 + (k0 & ~63) + swz(n, k0 & 63)] = p;
}

// ---------------------------------------------------------------------------
// X [8192][1024] f32 -> bf16, row-swizzled (key m&7) so gemm_bt's GLDS16
// A-staging lands fragments where the swz reads expect them.
__global__ __launch_bounds__(256)
void cvt2_kernel(const float* __restrict__ X0, const float* __restrict__ X1,
                 u16t* __restrict__ T0, u16t* __restrict__ T1) {
  int id = blockIdx.x * 256 + threadIdx.x;  // 8192 blocks -> 2097152 ids
  int wsel = id >> 20;
  int r = id & 1048575;
  int m = r >> 7;
  int k0 = (r & 127) << 3;
  const float* X = wsel == 0 ? X0 : X1;
  u16t* T = wsel == 0 ? T0 : T1;
  const float4* src = (const float4*)(X + (size_t)m * 1024 + k0);
  float4 a = src[0], b = src[1];
  uint4 p;
  p.x = pack2(a.y, a.x); p.y = pack2(a.w, a.z);
  p.z = pack2(b.y, b.x); p.w = pack2(b.w, b.z);
  *(uint4*)&T[(size_t)m * 1024 + (k0 & ~63) + swz(m, k0 & 63)] = p;
}

__global__ __launch_bounds__(256)
void cvt_kernel(const float* __restrict__ X, u16t* __restrict__ T) {
  int id = blockIdx.x * 256 + threadIdx.x;  // 4096 blocks -> 1048576 ids
  int m = id >> 7;
  int k0 = (id & 127) << 3;
  const float4* src = (const float4*)(X + (size_t)m * 1024 + k0);
  float4 a = src[0], b = src[1];
  uint4 p;
  p.x = pack2(a.y, a.x); p.y = pack2(a.w, a.z);
  p.z = pack2(b.y, b.x); p.w = pack2(b.w, b.z);
  *(uint4*)&T[(size_t)m * 1024 + (k0 & ~63) + swz(m, k0 & 63)] = p;
}

// ---------------------------------------------------------------------------
// C[8192,1024] = A[8192,1024] * BT^T + bias  (A, BT pre-swizzled bf16, both
// staged via GLDS16, LDS double-buffered with counted vmcnt).
// z=blockIdx.z selects the operand set (QK fusion).
// XCD remap: raw=by*8+bx; XCD c=raw&7 owns M-panels [c*8, c*8+8) for all 8
// N-blocks -> per-XCD L2 set ~4MB; A fetched once chip-wide.
// MODE 0: out bf16 swizzled [b,h,s,d], post-scale qsc (ln2^-1 for Q)
// MODE 1: out fp32 flat [m,n]
// MODE 2: out bf16 swizzled [b,h,d,s] with per-32 k-permutation p(k)
//         (matches attn's in-register P relabeling), row-scaled by sscv.
template <int MODE>
__global__ __launch_bounds__(256)
void gemm_bt(const u16t* __restrict__ Ap0, const u16t* __restrict__ Ap1,
             const u16t* __restrict__ BT0, const u16t* __restrict__ BT1,
             const float* __restrict__ bias0, const float* __restrict__ bias1,
             void* __restrict__ Cp0, void* __restrict__ Cp1,
             float sc0, float sc1, const float* __restrict__ sscv) {
  constexpr int K = 1024;
  __shared__ __align__(16) u16t lA[2][128 * 64];
  __shared__ __align__(16) u16t lB[2][128 * 64];
  const int z = blockIdx.z;
  const u16t* Ag = z ? Ap1 : Ap0;
  const u16t* BT = z ? BT1 : BT0;
  const float* bias = z ? bias1 : bias0;
  void* Cp = z ? Cp1 : Cp0;
  const float qsc = z ? sc1 : sc0;
  const int tid = threadIdx.x;
  const int lane = tid & 63, w = tid >> 6;
  const int wm = w >> 1, wn = w & 1;
  const int lrow = lane & 15, lq = lane >> 4;
  // XCD-grouping remap (dispatch id within z == by*8+bx; XCD = id%8)
  const int raw = blockIdx.y * 8 + blockIdx.x;
  const int xcd = raw & 7, slot = raw >> 3;
  const int m0 = (xcd * 8 + (slot >> 3)) * 128;
  const int n0 = (slot & 7) * 128;

  // stage K-step t (64 k) into buffer t&1: 8 GLDS16 per thread
  auto stage = [&](int t) {
    const int kb = t << 6;
    u16t* dA = lA[t & 1];
    u16t* dB = lB[t & 1];
#pragma unroll
    for (int i = 0; i < 4; ++i) {
      int chunk = w * 4 + i;
      int off = chunk * 1024 + lane * 16;  // byte offset in 16KB tile
      int r = off >> 7, ib = off & 127;
      GLDS16(Ag + (size_t)(m0 + r) * K + kb + (ib >> 1), &dA[chunk * 512]);
      GLDS16(BT + (size_t)(n0 + r) * K + kb + (ib >> 1), &dB[chunk * 512]);
    }
  };

  floatx4 acc[4][4];
#pragma unroll
  for (int i = 0; i < 4; ++i)
#pragma unroll
    for (int j = 0; j < 4; ++j) acc[i][j] = {0.f, 0.f, 0.f, 0.f};

  stage(0);
  stage(1);  // 16 loads in flight per thread

  for (int t = 0; t < 16; ++t) {
    if (t < 15) asm volatile("s_waitcnt vmcnt(8)" ::: "memory");  // buf t done
    else        asm volatile("s_waitcnt vmcnt(0)" ::: "memory");
    __builtin_amdgcn_s_barrier();
    const u16t* A_ = lA[t & 1];
    const u16t* B_ = lB[t & 1];
#pragma unroll
    for (int kk = 0; kk < 2; ++kk) {
      short8 af[4], bfr[4];
#pragma unroll
      for (int tt = 0; tt < 4; ++tt) {
        int ar = wm * 64 + tt * 16 + lrow;
        af[tt] = *(const short8*)&A_[ar * 64 + swz(ar, kk * 32 + lq * 8)];
      }
#pragma unroll
      for (int tt = 0; tt < 4; ++tt) {
        int br = wn * 64 + tt * 16 + lrow;
        bfr[tt] = *(const short8*)&B_[br * 64 + swz(br, kk * 32 + lq * 8)];
      }
      __builtin_amdgcn_s_setprio(1);
#pragma unroll
      for (int i = 0; i < 4; ++i)
#pragma unroll
        for (int j = 0; j < 4; ++j)
          acc[i][j] = MFMA16(af[i], bfr[j], acc[i][j]);
      __builtin_amdgcn_s_setprio(0);
    }
    asm volatile("s_waitcnt lgkmcnt(0)" ::: "memory");
    __builtin_amdgcn_s_barrier();  // all waves done reading buf t&1
    if (t < 14) stage(t + 2);      // refill the buffer just consumed
  }

  float bvv[4];
#pragma unroll
  for (int j = 0; j < 4; ++j) bvv[j] = bias[n0 + wn * 64 + j * 16 + lrow];
  const int h = (n0 + wn * 64) >> 6;  // head (MODE 0/2): constant per wave
#pragma unroll
  for (int i = 0; i < 4; ++i) {
#pragma unroll
    for (int r = 0; r < 4; ++r) {
      int rg = m0 + wm * 64 + i * 16 + lq * 4 + r;  // C/D: row=(lane>>4)*4+reg
      int b = rg >> 11, s = rg & 2047;
      float rs;
      if constexpr (MODE == 2) rs = sscv[(size_t)(b * NHEAD + h) * SEQ + s];
      else                     rs = qsc;
#pragma unroll
      for (int j = 0; j < 4; ++j) {
        int cg = n0 + wn * 64 + j * 16 + lrow;
        float v = acc[i][j][r] + bvv[j];
        if constexpr (MODE == 1) {
          ((float*)Cp)[(size_t)rg * 1024 + cg] = v;
        } else {
          v *= rs;
          int d = cg & 63;
          size_t bh = (size_t)(b * NHEAD + h);
          if constexpr (MODE == 0) {
            ((u16t*)Cp)[(bh * SEQ + s) * HDIM + swz(s, d)] = f2bf(v);
          } else {
            // per-32 column permutation p(k): position where k must sit so a
            // natural b128 read yields k = lq*4 + (e&3) + 16*(e>>2) at elem e
            int sp = (s & ~31) | (((s >> 2) & 3) << 3) | (s & 3) |
                     (((s >> 4) & 1) << 2);
            ((u16t*)Cp)[(bh * HDIM + d) * SEQ + (s & ~127) + swz(d, sp & 127)] =
                f2bf(v);
          }
        }
      }
    }
  }
}

// ---------------------------------------------------------------------------
// Column-softmax stats, exp2 domain, no max (S' bounded; see header):
//   ss[k] = 1 / (8 * sum_q 2^(S'[q,k])),  S' = Q' K^T with Q' = Q/ln2.
// Grid (64,16): x = bh so all col-tiles of one bh share an XCD's L2.
// (round-6 form: 32KB LDS, plain barriers — high occupancy)
__global__ __launch_bounds__(256)
void stats_kernel(const u16t* __restrict__ Qb, const u16t* __restrict__ Kb,
                  float* __restrict__ ss) {
  __shared__ __align__(16) u16t lK[128 * 64];
  __shared__ __align__(16) u16t lQ[128 * 64];
  const int tid = threadIdx.x, lane = tid & 63, w = tid >> 6;
  const int lrow = lane & 15, lq = lane >> 4;
  const int bh = blockIdx.x;
  const int c0 = blockIdx.y * 128;
  const u16t* Kbase = Kb + (size_t)bh * (SEQ * HDIM);
  const u16t* Qbase = Qb + (size_t)bh * (SEQ * HDIM);

#pragma unroll
  for (int i = 0; i < 4; ++i) {
    int chunk = w * 4 + i;
    GLDS16(Kbase + (size_t)c0 * HDIM + chunk * 512 + lane * 8, &lK[chunk * 512]);
  }

  short8 bfK[4];
  float lcur[2] = {0.f, 0.f};

  for (int q0 = 0; q0 < SEQ; q0 += 128) {
#pragma unroll
    for (int i = 0; i < 4; ++i) {
      int chunk = w * 4 + i;
      GLDS16(Qbase + (size_t)q0 * HDIM + chunk * 512 + lane * 8, &lQ[chunk * 512]);
    }
    __syncthreads();
    if (q0 == 0) {
#pragma unroll
      for (int nt = 0; nt < 2; ++nt) {
        int kr = w * 32 + nt * 16 + lrow;
        bfK[nt * 2]     = *(const short8*)&lK[kr * 64 + swz(kr, lq * 8)];
        bfK[nt * 2 + 1] = *(const short8*)&lK[kr * 64 + swz(kr, lq * 8 + 32)];
      }
    }
#pragma unroll
    for (int mt = 0; mt < 8; ++mt) {
      int qr = mt * 16 + lrow;
      short8 af0 = *(const short8*)&lQ[qr * 64 + swz(qr, lq * 8)];
      short8 af1 = *(const short8*)&lQ[qr * 64 + swz(qr, lq * 8 + 32)];
#pragma unroll
      for (int nt = 0; nt < 2; ++nt) {
        floatx4 a = {0.f, 0.f, 0.f, 0.f};
        a = MFMA16(af0, bfK[nt * 2], a);
        a = MFMA16(af1, bfK[nt * 2 + 1], a);
        lcur[nt] += EXP2(a[0]) + EXP2(a[1]) + EXP2(a[2]) + EXP2(a[3]);
      }
    }
    __syncthreads();
  }
  // lanes {l, l^16, l^32, l^48} hold disjoint q-subsets of the same column
#pragma unroll
  for (int t = 0; t < 2; ++t) {
    float ll = lcur[t];
    ll += __shfl_xor(ll, 16);
    ll += __shfl_xor(ll, 32);
    lcur[t] = ll;
  }
  if (lane < 16) {
#pragma unroll
    for (int t = 0; t < 2; ++t) {
      int col = c0 + w * 32 + t * 16 + lane;
      ss[(size_t)bh * SEQ + col] = 1.f / (8.f * lcur[t]);
    }
  }
}

// ---------------------------------------------------------------------------
// attn: per (b,h, 256-q tile): loop 128-k tiles (LDS double-buffered), each
// split into 4 32-k windows, software-pipelined WITHIN the wave:
//   prologue: QK(win 0) -> exp/pack -> pa
//   per window kw: issue QK MFMAs for kw+1, then PV(kw) MFMAs, then
//   exp/pack(kw+1) on the VALU while the matrix pipe drains PV.
// P relabeling: S^T acc lane layout IS the PV A-frag under the permuted
// contraction order; V' pre-permuted by gemm_bt<2>. Counted vmcnt(8), raw
// s_barrier, never vmcnt(0) mid-loop. LDS 64KB -> 2 blocks/CU.
__global__ __launch_bounds__(256, 2)
void attn_kernel(const u16t* __restrict__ Qb, const u16t* __restrict__ Kb,
                 const u16t* __restrict__ Vt, u16t* __restrict__ Hout) {
  __shared__ __align__(16) u16t sK[2][8192];   // [buf][128k x 64d]
  __shared__ __align__(16) u16t sV[2][8192];   // [buf][64d x 128k]
  const int tid = threadIdx.x, lane = tid & 63, w = tid >> 6;
  const int lrow = lane & 15, lq = lane >> 4;
  const int bh = blockIdx.x, q0 = blockIdx.y * 256;
  const size_t hb = (size_t)bh * (SEQ * HDIM);

  auto stage = [&](int t) {
    u16t* dK = sK[t & 1];
    u16t* dV = sV[t & 1];
    const int k0 = t << 7;
#pragma unroll
    for (int i = 0; i < 4; ++i) {
      int chunk = w * 4 + i;
      GLDS16(Kb + hb + (size_t)k0 * HDIM + chunk * 512 + lane * 8, &dK[chunk * 512]);
    }
#pragma unroll
    for (int i = 0; i < 4; ++i) {
      int chunk = w * 4 + i;
      int off = chunk * 1024 + lane * 16;
      int d = off >> 8, ib = off & 255;
      GLDS16(Vt + hb + ((size_t)d << 11) + k0 + (ib >> 1), &dV[chunk * 512]);
    }
  };
  auto loadK = [&](short8 dst[2][2], const u16t* K_, int kw) {
#pragma unroll
    for (int t = 0; t < 2; ++t) {
      int kr = (kw * 2 + t) * 16 + lrow;
      dst[t][0] = *(const short8*)&K_[kr * 64 + swz(kr, lq * 8)];
      dst[t][1] = *(const short8*)&K_[kr * 64 + swz(kr, lq * 8 + 32)];
    }
  };
  auto loadV = [&](short8 dst[4], const u16t* V_, int kw) {
#pragma unroll
    for (int dt = 0; dt < 4; ++dt) {
      int vr = dt * 16 + lrow;
      dst[dt] = *(const short8*)&V_[vr * 128 + swz(vr, kw * 32 + lq * 8)];
    }
  };

  // Stage the 32KB Q tile through sK (both buffers), lift 8 frags to regs.
  u16t* qs = (u16t*)sK;
#pragma unroll
  for (int i = 0; i < 8; ++i) {
    int chunk = w * 8 + i;
    GLDS16(Qb + hb + (size_t)q0 * HDIM + chunk * 512 + lane * 8, &qs[chunk * 512]);
  }
  __syncthreads();
  short8 bq[4][2];
#pragma unroll
  for (int j = 0; j < 4; ++j) {
    int qr = w * 64 + j * 16 + lrow;
    bq[j][0] = *(const short8*)&qs[qr * 64 + swz(qr, lq * 8)];
    bq[j][1] = *(const short8*)&qs[qr * 64 + swz(qr, lq * 8 + 32)];
  }
  __syncthreads();  // everyone has Q frags before stage(0) overwrites sK

  // QK issue: 16 MFMA for one 32-k window into s[j][half]
  auto qk = [&](const short8 ak[2][2], floatx4 s[4][2]) {
    __builtin_amdgcn_s_setprio(1);
#pragma unroll
    for (int j = 0; j < 4; ++j) {
      floatx4 a = {0.f, 0.f, 0.f, 0.f}, b = {0.f, 0.f, 0.f, 0.f};
      a = MFMA16(ak[0][0], bq[j][0], a);
      a = MFMA16(ak[0][1], bq[j][1], a);
      b = MFMA16(ak[1][0], bq[j][0], b);
      b = MFMA16(ak[1][1], bq[j][1], b);
      s[j][0] = a; s[j][1] = b;
    }
    __builtin_amdgcn_s_setprio(0);
  };
  // exp/pack: S -> P~ bf16 PV A-frags
  auto ep = [&](const floatx4 s[4][2], short8 pa[4]) {
#pragma unroll
    for (int j = 0; j < 4; ++j) {
      uintx4 pw;
      pw[0] = cvtpk(EXP2(s[j][0][0]), EXP2(s[j][0][1]));
      pw[1] = cvtpk(EXP2(s[j][0][2]), EXP2(s[j][0][3]));
      pw[2] = cvtpk(EXP2(s[j][1][0]), EXP2(s[j][1][1]));
      pw[3] = cvtpk(EXP2(s[j][1][2]), EXP2(s[j][1][3]));
      pa[j] = __builtin_bit_cast(short8, pw);
    }
  };

  floatx4 ao[4][4];
#pragma unroll
  for (int j = 0; j < 4; ++j)
#pragma unroll
    for (int t = 0; t < 4; ++t) ao[j][t] = {0.f, 0.f, 0.f, 0.f};

  stage(0);
  stage(1);  // 16 loads in flight

#pragma unroll 2
  for (int kt = 0; kt < 16; ++kt) {
    if (kt < 15) asm volatile("s_waitcnt vmcnt(8)" ::: "memory");  // kt done
    else         asm volatile("s_waitcnt vmcnt(0)" ::: "memory");
    __builtin_amdgcn_s_barrier();
    const u16t* K_ = sK[kt & 1];
    const u16t* V_ = sV[kt & 1];

    // prologue: QK + exp/pack for window 0
    short8 ak0[2][2];
    loadK(ak0, K_, 0);
    floatx4 s0[4][2];
    qk(ak0, s0);
    short8 pa[4];
    ep(s0, pa);

#pragma unroll
    for (int kw = 0; kw < 4; ++kw) {
      short8 bv[4];
      loadV(bv, V_, kw);
      short8 akN[2][2];
      floatx4 sN[4][2];
      if (kw < 3) {
        loadK(akN, K_, kw + 1);
        qk(akN, sN);               // next window's QK issued BEFORE this PV
      }
      __builtin_amdgcn_s_setprio(1);
#pragma unroll
      for (int dt = 0; dt < 4; ++dt)
#pragma unroll
        for (int j = 0; j < 4; ++j)
          ao[j][dt] = MFMA16(pa[j], bv[dt], ao[j][dt]);
      __builtin_amdgcn_s_setprio(0);
      if (kw < 3) {
        short8 paN[4];
        ep(sN, paN);               // exps overlap the PV drain
#pragma unroll
        for (int j = 0; j < 4; ++j) pa[j] = paN[j];
      }
    }

    asm volatile("s_waitcnt lgkmcnt(0)" ::: "memory");
    __builtin_amdgcn_s_barrier();  // all waves done reading buf kt&1
    if (kt < 14) stage(kt + 2);    // refill the buffer just consumed
  }

  // Hout[b][q][h*64+d], swizzled (key q&7) for gemm_bt<1>'s GLDS16 staging
  const int b = bh >> 4, h = bh & 15;
#pragma unroll
  for (int j = 0; j < 4; ++j)
#pragma unroll
    for (int dt = 0; dt < 4; ++dt) {
      int d = dt * 16 + lrow;
#pragma unroll
      for (int r = 0; r < 4; ++r) {
        int q = q0 + w * 64 + j * 16 + lq * 4 + r;
        Hout[((size_t)b * SEQ + q) * DMODEL + h * HDIM + swz(q, d)] = f2bf(ao[j][dt][r]);
      }
    }
}

// ---------------------------------------------------------------------------
extern "C" void kernel_launch(void* const* d_in, const int* in_sizes, int n_in,
                              void* d_out, int out_size, void* d_ws, size_t ws_size,
                              hipStream_t stream) {
  (void)in_sizes; (void)n_in; (void)out_size; (void)ws_size;
  const float* queries = (const float*)d_in[0];
  const float* keys    = (const float*)d_in[1];
  const float* values  = (const float*)d_in[2];
  const float* Wq = (const float*)d_in[3];
  const float* bq = (const float*)d_in[4];
  const float* Wk = (const float*)d_in[5];
  const float* bk = (const float*)d_in[6];
  const float* Wv = (const float*)d_in[7];
  const float* bv = (const float*)d_in[8];
  const float* Wo = (const float*)d_in[9];
  const float* bo = (const float*)d_in[10];

  char* ws = (char*)d_ws;
  const size_t MB = 1024 * 1024;
  u16t* Qb   = (u16t*)(ws + 0 * MB);    // [b,h,s,d] bf16 swizzled (x 1/ln2)
  u16t* Kb   = (u16t*)(ws + 16 * MB);   // [b,h,s,d] bf16 swizzled
  u16t* qcv  = (u16t*)(ws + 32 * MB);   // cvt(queries); dead after QK proj
  u16t* vcv  = qcv;                     // cvt(values), written after QK proj
  u16t* Hout = qcv;                     // aliases again (attn after gemm2)
  u16t* kcv  = (u16t*)(ws + 48 * MB);   // cvt(keys); dead after QK proj
  u16t* Vt   = kcv;                     // aliases kcv (V proj runs later)
  u16t* wqt  = (u16t*)(ws + 64 * MB);   // [n][k] bf16 swizzled, 2MB each
  u16t* wkt  = (u16t*)(ws + 66 * MB);
  u16t* wvt  = (u16t*)(ws + 68 * MB);
  u16t* wot  = (u16t*)(ws + 70 * MB);
  float* ssc = (float*)(ws + 72 * MB);  // [bh][s] 1/(8*sum 2^S')

  wt_kernel<<<2048, 256, 0, stream>>>(Wq, Wk, Wv, Wo, wqt, wkt, wvt, wot);

  cvt2_kernel<<<8192, 256, 0, stream>>>(queries, keys, qcv, kcv);

  gemm_bt<0><<<dim3(8, 64, 2), 256, 0, stream>>>(
      qcv, kcv, wqt, wkt, bq, bk, Qb, Kb, 1.44269504f, 1.0f, nullptr);

  cvt_kernel<<<4096, 256, 0, stream>>>(values, vcv);  // qcv region now dead

  stats_kernel<<<dim3(64, 16), 256, 0, stream>>>(Qb, Kb, ssc);

  gemm_bt<2><<<dim3(8, 64, 1), 256, 0, stream>>>(
      vcv, vcv, wvt, wvt, bv, bv, Vt, Vt, 1.0f, 1.0f, ssc);

  attn_kernel<<<dim3(64, 8), 256, 0, stream>>>(Qb, Kb, Vt, Hout);

  gemm_bt<1><<<dim3(8, 64, 1), 256, 0, stream>>>(
      Hout, Hout, wot, wot, bo, bo, d_out, d_out, 1.0f, 1.0f, nullptr);
}

// Round 9
// 378.568 us; speedup vs baseline: 1.0070x; 1.0070x over previous
//
#include <hip/hip_runtime.h>
#include <cstddef>

// ============================================================================
// MaskedMultiHeadAttention (B=4,S=2048,DM=1024,H=16,HD=64), faithful to ref:
//   softmax over the QUERY axis (axis=2), then /sqrt(HD); mask is a no-op.
// Round 12: pipeline restructure (5 dispatches, was 8):
//   - stats now emits lss[k] = -3 - log2(sum_q 2^S') (log2-domain normalizer).
//   - attn folds the normalizer for FREE: QK^T MFMA C-operand is initialized
//     with lss (C/D row = k, col = q; lss is k-only -> broadcast ds_read).
//     P~ = 2^(S' + lss) <= 1. V is no longer pre-scaled.
//   - V-proj thus loses its stats dependency -> ONE fused proj dispatch z=3
//     (Q,K,V) with the proven f32-A-pack staging (no cvt buffers/launches,
//     1536 blocks = 5 blocks/CU vs 2). Workspace stays 72.5 MB.
//   - out-proj gemm reverted to the proven r9 single-buffer form (r10/r11
//     dbuf measured neutral: it traded 4->2 blocks/CU for the pipeline).
// Order: wt -> proj(z=3) -> stats -> attn -> outproj.
// ============================================================================

typedef unsigned short u16t;
typedef __attribute__((ext_vector_type(8))) short short8;
typedef __attribute__((ext_vector_type(4))) float floatx4;
typedef __attribute__((ext_vector_type(4))) unsigned int uintx4;

#define MFMA16(a, b, c) __builtin_amdgcn_mfma_f32_16x16x32_bf16((a), (b), (c), 0, 0, 0)
#define GLDS16(g, l)                                                        \
  __builtin_amdgcn_global_load_lds(                                         \
      (const __attribute__((address_space(1))) unsigned int*)(g),           \
      (__attribute__((address_space(3))) unsigned int*)(l), 16, 0, 0)
#define GLDS4(g, l)                                                         \
  __builtin_amdgcn_global_load_lds(                                         \
      (const __attribute__((address_space(1))) unsigned int*)(g),           \
      (__attribute__((address_space(3))) unsigned int*)(l), 4, 0, 0)

#if __has_builtin(__builtin_amdgcn_exp2f)
#define EXP2(x) __builtin_amdgcn_exp2f(x)
#else
#define EXP2(x) __expf(0.69314718f * (x))
#endif

static __device__ __forceinline__ u16t f2bf(float f) {
  union { float f; unsigned u; } v; v.f = f;
  unsigned r = v.u + 0x7FFFu + ((v.u >> 16) & 1u);  // RNE
  return (u16t)(r >> 16);
}
// Pack two f32 -> two bf16 (round-half-up) in one v_perm: hi<<16 | lo.
static __device__ __forceinline__ unsigned pack2(float hi, float lo) {
  union { float f; unsigned u; } a, b; a.f = hi; b.f = lo;
  return __builtin_amdgcn_perm(a.u + 0x8000u, b.u + 0x8000u, 0x07060302u);
}
// HW packed f32->bf16 (RNE): D = {hi16=cvt(hi), lo16=cvt(lo)} in one VALU op.
static __device__ __forceinline__ unsigned cvtpk(float lo, float hi) {
  unsigned r;
  asm("v_cvt_pk_bf16_f32 %0, %1, %2" : "=v"(r) : "v"(lo), "v"(hi));
  return r;
}

// XOR swizzle within a 64/128-elem row block: breaks 128B/256B bank period.
static __device__ __forceinline__ int swz(int row, int col) {
  return (((col >> 3) ^ (row & 7)) << 3) | (col & 7);
}

#define SEQ    2048
#define NHEAD  16
#define HDIM   64
#define DMODEL 1024

// ---------------------------------------------------------------------------
// All four W [1024][1024] f32 -> WT [n][k-swizzled] bf16 in one dispatch.
__global__ __launch_bounds__(256)
void wt_kernel(const float* __restrict__ W0, const float* __restrict__ W1,
               const float* __restrict__ W2, const float* __restrict__ W3,
               u16t* __restrict__ T0, u16t* __restrict__ T1,
               u16t* __restrict__ T2, u16t* __restrict__ T3) {
  int id = blockIdx.x * 256 + threadIdx.x;  // 2048 blocks -> 524288 ids
  int wsel = id >> 17;
  int r = id & 131071;
  int n = r & 1023;
  int k0 = (r >> 10) << 3;
  const float* W = wsel == 0 ? W0 : wsel == 1 ? W1 : wsel == 2 ? W2 : W3;
  u16t* T = wsel == 0 ? T0 : wsel == 1 ? T1 : wsel == 2 ? T2 : T3;
  const float* src = W + (size_t)k0 * 1024 + n;
  float f[8];
#pragma unroll
  for (int i = 0; i < 8; ++i) f[i] = src[(size_t)i * 1024];
  uint4 p;
  p.x = pack2(f[1], f[0]); p.y = pack2(f[3], f[2]);
  p.z = pack2(f[5], f[4]); p.w = pack2(f[7], f[6]);
  *(uint4*)&T[(size_t)n * 1024 + (k0 & ~63) + swz(n, k0 & 63)] = p;
}

// ---------------------------------------------------------------------------
// Fused QKV projection, grid (8,64,3): z selects {A, W, bias, C, epilogue}.
// A is f32 (queries/keys/values), packed to bf16 in-kernel during staging
// (proven r6 path); W pre-swizzled bf16 via GLDS16.
// z=0: Qb [b,h,s,d] swizzled, x 1/ln2.  z=1: Kb same, x1.
// z=2: Vt [b,h,d,s] swizzled with per-32 k-permutation p(k) (attn layout).
// XCD remap: raw=by*8+bx within slice; per-XCD L2 set ~4MB.
__global__ __launch_bounds__(256)
void proj_kernel(const float* __restrict__ Qf, const float* __restrict__ Kf,
                 const float* __restrict__ Vf,
                 const u16t* __restrict__ WQ, const u16t* __restrict__ WK,
                 const u16t* __restrict__ WV,
                 const float* __restrict__ bq, const float* __restrict__ bk,
                 const float* __restrict__ bv,
                 u16t* __restrict__ Qb, u16t* __restrict__ Kb,
                 u16t* __restrict__ Vt) {
  constexpr int K = 1024;
  __shared__ __align__(16) u16t lA[128 * 64];
  __shared__ __align__(16) u16t lB[128 * 64];
  const int z = blockIdx.z;
  const float* Ag = z == 0 ? Qf : z == 1 ? Kf : Vf;
  const u16t* BT = z == 0 ? WQ : z == 1 ? WK : WV;
  const float* bias = z == 0 ? bq : z == 1 ? bk : bv;
  const float qsc = z == 0 ? 1.44269504f : 1.0f;
  const int tid = threadIdx.x;
  const int lane = tid & 63, w = tid >> 6;
  const int wm = w >> 1, wn = w & 1;
  const int lrow = lane & 15, lq = lane >> 4;
  const int raw = blockIdx.y * 8 + blockIdx.x;
  const int xcd = raw & 7, slot = raw >> 3;
  const int m0 = (xcd * 8 + (slot >> 3)) * 128;
  const int n0 = (slot & 7) * 128;

  floatx4 acc[4][4];
#pragma unroll
  for (int i = 0; i < 4; ++i)
#pragma unroll
    for (int j = 0; j < 4; ++j) acc[i][j] = {0.f, 0.f, 0.f, 0.f};

  for (int kb = 0; kb < K; kb += 64) {
#pragma unroll
    for (int i = 0; i < 8; ++i) {
      int e = (i * 256 + tid) * 4;  // element in 128x64 tile
      int r = e >> 6, c = e & 63;
      const float* src = Ag + (size_t)(m0 + r) * K + kb + c;
      uint2 p;
      p.x = pack2(src[1], src[0]);
      p.y = pack2(src[3], src[2]);
      *(uint2*)&lA[r * 64 + swz(r, c)] = p;
    }
#pragma unroll
    for (int i = 0; i < 4; ++i) {
      int chunk = w * 4 + i;
      int off = chunk * 1024 + lane * 16;
      int r = off >> 7, ib = off & 127;
      GLDS16(BT + (size_t)(n0 + r) * K + kb + (ib >> 1), &lB[chunk * 512]);
    }
    __syncthreads();
#pragma unroll
    for (int kk = 0; kk < 2; ++kk) {
      short8 af[4], bfr[4];
#pragma unroll
      for (int t = 0; t < 4; ++t) {
        int ar = wm * 64 + t * 16 + lrow;
        af[t] = *(const short8*)&lA[ar * 64 + swz(ar, kk * 32 + lq * 8)];
      }
#pragma unroll
      for (int t = 0; t < 4; ++t) {
        int br = wn * 64 + t * 16 + lrow;
        bfr[t] = *(const short8*)&lB[br * 64 + swz(br, kk * 32 + lq * 8)];
      }
#pragma unroll
      for (int i = 0; i < 4; ++i)
#pragma unroll
        for (int j = 0; j < 4; ++j)
          acc[i][j] = MFMA16(af[i], bfr[j], acc[i][j]);
    }
    __syncthreads();
  }

  float bvv[4];
#pragma unroll
  for (int j = 0; j < 4; ++j) bvv[j] = bias[n0 + wn * 64 + j * 16 + lrow];
  const int h = (n0 + wn * 64) >> 6;  // head: constant per wave
  u16t* Out = z == 0 ? Qb : Kb;       // z==2 handled separately
#pragma unroll
  for (int i = 0; i < 4; ++i) {
#pragma unroll
    for (int r = 0; r < 4; ++r) {
      int rg = m0 + wm * 64 + i * 16 + lq * 4 + r;  // C/D: row=(lane>>4)*4+reg
      int b = rg >> 11, s = rg & 2047;
      size_t bh = (size_t)(b * NHEAD + h);
#pragma unroll
      for (int j = 0; j < 4; ++j) {
        int cg = n0 + wn * 64 + j * 16 + lrow;
        int d = cg & 63;
        float v = acc[i][j][r] + bvv[j];
        if (z < 2) {
          Out[(bh * SEQ + s) * HDIM + swz(s, d)] = f2bf(v * qsc);
        } else {
          // per-32 column permutation p(k): position where k must sit so a
          // natural b128 read yields k = lq*4 + (e&3) + 16*(e>>2) at elem e
          int sp = (s & ~31) | (((s >> 2) & 3) << 3) | (s & 3) |
                   (((s >> 4) & 1) << 2);
          Vt[(bh * HDIM + d) * SEQ + (s & ~127) + swz(d, sp & 127)] = f2bf(v);
        }
      }
    }
  }
}

// ---------------------------------------------------------------------------
// Column-softmax stats, exp2 domain, no max (S' bounded; see header):
//   lss[k] = -3 - log2( sum_q 2^(S'[q,k]) ),  S' = Q' K^T with Q' = Q/ln2.
// (so 2^(S' + lss) = softmax_q / 8 = softmax_q / sqrt(HD))
// Grid (64,16): x = bh so all col-tiles of one bh share an XCD's L2.
__global__ __launch_bounds__(256)
void stats_kernel(const u16t* __restrict__ Qb, const u16t* __restrict__ Kb,
                  float* __restrict__ lss) {
  __shared__ __align__(16) u16t lK[128 * 64];
  __shared__ __align__(16) u16t lQ[128 * 64];
  const int tid = threadIdx.x, lane = tid & 63, w = tid >> 6;
  const int lrow = lane & 15, lq = lane >> 4;
  const int bh = blockIdx.x;
  const int c0 = blockIdx.y * 128;
  const u16t* Kbase = Kb + (size_t)bh * (SEQ * HDIM);
  const u16t* Qbase = Qb + (size_t)bh * (SEQ * HDIM);

#pragma unroll
  for (int i = 0; i < 4; ++i) {
    int chunk = w * 4 + i;
    GLDS16(Kbase + (size_t)c0 * HDIM + chunk * 512 + lane * 8, &lK[chunk * 512]);
  }

  short8 bfK[4];
  float lcur[2] = {0.f, 0.f};

  for (int q0 = 0; q0 < SEQ; q0 += 128) {
#pragma unroll
    for (int i = 0; i < 4; ++i) {
      int chunk = w * 4 + i;
      GLDS16(Qbase + (size_t)q0 * HDIM + chunk * 512 + lane * 8, &lQ[chunk * 512]);
    }
    __syncthreads();
    if (q0 == 0) {
#pragma unroll
      for (int nt = 0; nt < 2; ++nt) {
        int kr = w * 32 + nt * 16 + lrow;
        bfK[nt * 2]     = *(const short8*)&lK[kr * 64 + swz(kr, lq * 8)];
        bfK[nt * 2 + 1] = *(const short8*)&lK[kr * 64 + swz(kr, lq * 8 + 32)];
      }
    }
#pragma unroll
    for (int mt = 0; mt < 8; ++mt) {
      int qr = mt * 16 + lrow;
      short8 af0 = *(const short8*)&lQ[qr * 64 + swz(qr, lq * 8)];
      short8 af1 = *(const short8*)&lQ[qr * 64 + swz(qr, lq * 8 + 32)];
#pragma unroll
      for (int nt = 0; nt < 2; ++nt) {
        floatx4 a = {0.f, 0.f, 0.f, 0.f};
        a = MFMA16(af0, bfK[nt * 2], a);
        a = MFMA16(af1, bfK[nt * 2 + 1], a);
        lcur[nt] += EXP2(a[0]) + EXP2(a[1]) + EXP2(a[2]) + EXP2(a[3]);
      }
    }
    __syncthreads();
  }
  // lanes {l, l^16, l^32, l^48} hold disjoint q-subsets of the same column
#pragma unroll
  for (int t = 0; t < 2; ++t) {
    float ll = lcur[t];
    ll += __shfl_xor(ll, 16);
    ll += __shfl_xor(ll, 32);
    lcur[t] = ll;
  }
  if (lane < 16) {
#pragma unroll
    for (int t = 0; t < 2; ++t) {
      int col = c0 + w * 32 + t * 16 + lane;
      lss[(size_t)bh * SEQ + col] = -3.0f - __log2f(lcur[t]);
    }
  }
}

// ---------------------------------------------------------------------------
// attn: per (b,h, 256-q tile): loop 128-k tiles (LDS double-buffered), each
// split into 4 32-k windows, software-pipelined WITHIN the wave (r9 form):
//   prologue: QK(win 0) -> exp/pack; per window: QK(kw+1) before PV(kw),
//   exp/pack(kw+1) after PV-issue.
// NEW: QK MFMA C-operand is initialized with lss[k] (k-only -> broadcast
// ds_read_b128 from a tiny staged lss tile), so P~ = 2^(S'+lss) is the
// normalized softmax/8 directly; V is unscaled.
// Counted vmcnt(10) (10 loads/stage: 4 K + 4 V + 2 lss), raw s_barrier,
// never vmcnt(0) mid-loop. LDS 65KB -> 2 blocks/CU.
__global__ __launch_bounds__(256, 2)
void attn_kernel(const u16t* __restrict__ Qb, const u16t* __restrict__ Kb,
                 const u16t* __restrict__ Vt, const float* __restrict__ Lb,
                 u16t* __restrict__ Hout) {
  __shared__ __align__(16) u16t sK[2][8192];   // [buf][128k x 64d]
  __shared__ __align__(16) u16t sV[2][8192];   // [buf][64d x 128k]
  __shared__ __align__(16) float sL[2][128];   // [buf][128k] lss tile
  const int tid = threadIdx.x, lane = tid & 63, w = tid >> 6;
  const int lrow = lane & 15, lq = lane >> 4;
  const int bh = blockIdx.x, q0 = blockIdx.y * 256;
  const size_t hb = (size_t)bh * (SEQ * HDIM);
  const float* Lg = Lb + (size_t)bh * SEQ;

  auto stage = [&](int t) {
    u16t* dK = sK[t & 1];
    u16t* dV = sV[t & 1];
    float* dL = sL[t & 1];
    const int k0 = t << 7;
#pragma unroll
    for (int i = 0; i < 4; ++i) {
      int chunk = w * 4 + i;
      GLDS16(Kb + hb + (size_t)k0 * HDIM + chunk * 512 + lane * 8, &dK[chunk * 512]);
    }
#pragma unroll
    for (int i = 0; i < 4; ++i) {
      int chunk = w * 4 + i;
      int off = chunk * 1024 + lane * 16;
      int d = off >> 8, ib = off & 255;
      GLDS16(Vt + hb + ((size_t)d << 11) + k0 + (ib >> 1), &dV[chunk * 512]);
    }
    GLDS4(Lg + k0 + lane, &dL[0]);        // lanes -> dL[0..63]
    GLDS4(Lg + k0 + 64 + lane, &dL[64]);  // lanes -> dL[64..127]
  };
  auto loadK = [&](short8 dst[2][2], const u16t* K_, int kw) {
#pragma unroll
    for (int t = 0; t < 2; ++t) {
      int kr = (kw * 2 + t) * 16 + lrow;
      dst[t][0] = *(const short8*)&K_[kr * 64 + swz(kr, lq * 8)];
      dst[t][1] = *(const short8*)&K_[kr * 64 + swz(kr, lq * 8 + 32)];
    }
  };
  auto loadV = [&](short8 dst[4], const u16t* V_, int kw) {
#pragma unroll
    for (int dt = 0; dt < 4; ++dt) {
      int vr = dt * 16 + lrow;
      dst[dt] = *(const short8*)&V_[vr * 128 + swz(vr, kw * 32 + lq * 8)];
    }
  };

  // Stage the 32KB Q tile through sK (both buffers), lift 8 frags to regs.
  u16t* qs = (u16t*)sK;
#pragma unroll
  for (int i = 0; i < 8; ++i) {
    int chunk = w * 8 + i;
    GLDS16(Qb + hb + (size_t)q0 * HDIM + chunk * 512 + lane * 8, &qs[chunk * 512]);
  }
  __syncthreads();
  short8 bq[4][2];
#pragma unroll
  for (int j = 0; j < 4; ++j) {
    int qr = w * 64 + j * 16 + lrow;
    bq[j][0] = *(const short8*)&qs[qr * 64 + swz(qr, lq * 8)];
    bq[j][1] = *(const short8*)&qs[qr * 64 + swz(qr, lq * 8 + 32)];
  }
  __syncthreads();  // everyone has Q frags before stage(0) overwrites sK

  // QK issue: 16 MFMA for one 32-k window; C-in = lss broadcast (cA, cB)
  auto qk = [&](const short8 ak[2][2], floatx4 s[4][2], floatx4 cA, floatx4 cB) {
    __builtin_amdgcn_s_setprio(1);
#pragma unroll
    for (int j = 0; j < 4; ++j) {
      floatx4 a = cA, b = cB;
      a = MFMA16(ak[0][0], bq[j][0], a);
      a = MFMA16(ak[0][1], bq[j][1], a);
      b = MFMA16(ak[1][0], bq[j][0], b);
      b = MFMA16(ak[1][1], bq[j][1], b);
      s[j][0] = a; s[j][1] = b;
    }
    __builtin_amdgcn_s_setprio(0);
  };
  // exp/pack: S -> P~ bf16 PV A-frags
  auto ep = [&](const floatx4 s[4][2], short8 pa[4]) {
#pragma unroll
    for (int j = 0; j < 4; ++j) {
      uintx4 pw;
      pw[0] = cvtpk(EXP2(s[j][0][0]), EXP2(s[j][0][1]));
      pw[1] = cvtpk(EXP2(s[j][0][2]), EXP2(s[j][0][3]));
      pw[2] = cvtpk(EXP2(s[j][1][0]), EXP2(s[j][1][1]));
      pw[3] = cvtpk(EXP2(s[j][1][2]), EXP2(s[j][1][3]));
      pa[j] = __builtin_bit_cast(short8, pw);
    }
  };

  floatx4 ao[4][4];
#pragma unroll
  for (int j = 0; j < 4; ++j)
#pragma unroll
    for (int t = 0; t < 4; ++t) ao[j][t] = {0.f, 0.f, 0.f, 0.f};

  stage(0);
  stage(1);  // 20 loads in flight

#pragma unroll 2
  for (int kt = 0; kt < 16; ++kt) {
    if (kt < 15) asm volatile("s_waitcnt vmcnt(10)" ::: "memory");  // kt done
    else         asm volatile("s_waitcnt vmcnt(0)" ::: "memory");
    __builtin_amdgcn_s_barrier();
    const u16t* K_ = sK[kt & 1];
    const u16t* V_ = sV[kt & 1];
    const float* L_ = sL[kt & 1];

    // prologue: QK + exp/pack for window 0
    short8 ak0[2][2];
    loadK(ak0, K_, 0);
    floatx4 cA = *(const floatx4*)&L_[lq * 4];
    floatx4 cB = *(const floatx4*)&L_[16 + lq * 4];
    floatx4 s0[4][2];
    qk(ak0, s0, cA, cB);
    short8 pa[4];
    ep(s0, pa);

#pragma unroll
    for (int kw = 0; kw < 4; ++kw) {
      short8 bv[4];
      loadV(bv, V_, kw);
      short8 akN[2][2];
      floatx4 sN[4][2];
      if (kw < 3) {
        loadK(akN, K_, kw + 1);
        floatx4 cAn = *(const floatx4*)&L_[(kw + 1) * 32 + lq * 4];
        floatx4 cBn = *(const floatx4*)&L_[(kw + 1) * 32 + 16 + lq * 4];
        qk(akN, sN, cAn, cBn);     // next window's QK issued BEFORE this PV
      }
      __builtin_amdgcn_s_setprio(1);
#pragma unroll
      for (int dt = 0; dt < 4; ++dt)
#pragma unroll
        for (int j = 0; j < 4; ++j)
          ao[j][dt] = MFMA16(pa[j], bv[dt], ao[j][dt]);
      __builtin_amdgcn_s_setprio(0);
      if (kw < 3) {
        short8 paN[4];
        ep(sN, paN);               // exps overlap the PV drain
#pragma unroll
        for (int j = 0; j < 4; ++j) pa[j] = paN[j];
      }
    }

    asm volatile("s_waitcnt lgkmcnt(0)" ::: "memory");
    __builtin_amdgcn_s_barrier();  // all waves done reading buf kt&1
    if (kt < 14) stage(kt + 2);    // refill the buffer just consumed
  }

  // Hout[b][q][h*64+d], swizzled (key q&7) for outproj's GLDS16 staging
  const int b = bh >> 4, h = bh & 15;
#pragma unroll
  for (int j = 0; j < 4; ++j)
#pragma unroll
    for (int dt = 0; dt < 4; ++dt) {
      int d = dt * 16 + lrow;
#pragma unroll
      for (int r = 0; r < 4; ++r) {
        int q = q0 + w * 64 + j * 16 + lq * 4 + r;
        Hout[((size_t)b * SEQ + q) * DMODEL + h * HDIM + swz(q, d)] = f2bf(ao[j][dt][r]);
      }
    }
}

// ---------------------------------------------------------------------------
// Out-projection: C[8192,1024] f32 = Hout[8192,1024](bf16 swz) * WO^T + bias.
// r9's proven single-buffer GLDS16 loop (4 blocks/CU at 32KB... grid 512=2/CU).
__global__ __launch_bounds__(256)
void outproj_kernel(const u16t* __restrict__ Ag, const u16t* __restrict__ BT,
                    const float* __restrict__ bias, float* __restrict__ Cp) {
  constexpr int K = 1024;
  __shared__ __align__(16) u16t lA[128 * 64];
  __shared__ __align__(16) u16t lB[128 * 64];
  const int tid = threadIdx.x;
  const int lane = tid & 63, w = tid >> 6;
  const int wm = w >> 1, wn = w & 1;
  const int lrow = lane & 15, lq = lane >> 4;
  const int raw = blockIdx.y * 8 + blockIdx.x;
  const int xcd = raw & 7, slot = raw >> 3;
  const int m0 = (xcd * 8 + (slot >> 3)) * 128;
  const int n0 = (slot & 7) * 128;

  floatx4 acc[4][4];
#pragma unroll
  for (int i = 0; i < 4; ++i)
#pragma unroll
    for (int j = 0; j < 4; ++j) acc[i][j] = {0.f, 0.f, 0.f, 0.f};

  for (int kb = 0; kb < K; kb += 64) {
#pragma unroll
    for (int i = 0; i < 4; ++i) {
      int chunk = w * 4 + i;
      int off = chunk * 1024 + lane * 16;
      int r = off >> 7, ib = off & 127;
      GLDS16(Ag + (size_t)(m0 + r) * K + kb + (ib >> 1), &lA[chunk * 512]);
      GLDS16(BT + (size_t)(n0 + r) * K + kb + (ib >> 1), &lB[chunk * 512]);
    }
    __syncthreads();
#pragma unroll
    for (int kk = 0; kk < 2; ++kk) {
      short8 af[4], bfr[4];
#pragma unroll
      for (int t = 0; t < 4; ++t) {
        int ar = wm * 64 + t * 16 + lrow;
        af[t] = *(const short8*)&lA[ar * 64 + swz(ar, kk * 32 + lq * 8)];
      }
#pragma unroll
      for (int t = 0; t < 4; ++t) {
        int br = wn * 64 + t * 16 + lrow;
        bfr[t] = *(const short8*)&lB[br * 64 + swz(br, kk * 32 + lq * 8)];
      }
#pragma unroll
      for (int i = 0; i < 4; ++i)
#pragma unroll
        for (int j = 0; j < 4; ++j)
          acc[i][j] = MFMA16(af[i], bfr[j], acc[i][j]);
    }
    __syncthreads();
  }

  float bvv[4];
#pragma unroll
  for (int j = 0; j < 4; ++j) bvv[j] = bias[n0 + wn * 64 + j * 16 + lrow];
#pragma unroll
  for (int i = 0; i < 4; ++i) {
#pragma unroll
    for (int r = 0; r < 4; ++r) {
      int rg = m0 + wm * 64 + i * 16 + lq * 4 + r;
#pragma unroll
      for (int j = 0; j < 4; ++j) {
        int cg = n0 + wn * 64 + j * 16 + lrow;
        Cp[(size_t)rg * 1024 + cg] = acc[i][j][r] + bvv[j];
      }
    }
  }
}

// ---------------------------------------------------------------------------
extern "C" void kernel_launch(void* const* d_in, const int* in_sizes, int n_in,
                              void* d_out, int out_size, void* d_ws, size_t ws_size,
                              hipStream_t stream) {
  (void)in_sizes; (void)n_in; (void)out_size; (void)ws_size;
  const float* queries = (const float*)d_in[0];
  const float* keys    = (const float*)d_in[1];
  const float* values  = (const float*)d_in[2];
  const float* Wq = (const float*)d_in[3];
  const float* bq = (const float*)d_in[4];
  const float* Wk = (const float*)d_in[5];
  const float* bk = (const float*)d_in[6];
  const float* Wv = (const float*)d_in[7];
  const float* bv = (const float*)d_in[8];
  const float* Wo = (const float*)d_in[9];
  const float* bo = (const float*)d_in[10];

  char* ws = (char*)d_ws;
  const size_t MB = 1024 * 1024;
  u16t* Qb   = (u16t*)(ws + 0 * MB);    // [b,h,s,d] bf16 swizzled (x 1/ln2)
  u16t* Kb   = (u16t*)(ws + 16 * MB);   // [b,h,s,d] bf16 swizzled
  u16t* Hout = (u16t*)(ws + 32 * MB);   // [b,s,dm] bf16 swizzled
  u16t* Vt   = (u16t*)(ws + 48 * MB);   // [b,h,d,s] bf16 swz+perm (unscaled)
  u16t* wqt  = (u16t*)(ws + 64 * MB);   // [n][k] bf16 swizzled, 2MB each
  u16t* wkt  = (u16t*)(ws + 66 * MB);
  u16t* wvt  = (u16t*)(ws + 68 * MB);
  u16t* wot  = (u16t*)(ws + 70 * MB);
  float* lss = (float*)(ws + 72 * MB);  // [bh][s]  -3 - log2(sum 2^S')

  wt_kernel<<<2048, 256, 0, stream>>>(Wq, Wk, Wv, Wo, wqt, wkt, wvt, wot);

  proj_kernel<<<dim3(8, 64, 3), 256, 0, stream>>>(
      queries, keys, values, wqt, wkt, wvt, bq, bk, bv, Qb, Kb, Vt);

  stats_kernel<<<dim3(64, 16), 256, 0, stream>>>(Qb, Kb, lss);

  attn_kernel<<<dim3(64, 8), 256, 0, stream>>>(Qb, Kb, Vt, lss, Hout);

  outproj_kernel<<<dim3(8, 64), 256, 0, stream>>>(Hout, wot, bo, (float*)d_out);
}

// Round 10
// 377.339 us; speedup vs baseline: 1.0103x; 1.0033x over previous
//
#include <hip/hip_runtime.h>
#include <cstddef>

// ============================================================================
// MaskedMultiHeadAttention (B=4,S=2048,DM=1024,H=16,HD=64), faithful to ref:
//   softmax over the QUERY axis (axis=2), then /sqrt(HD); mask is a no-op.
// Round 13: proj_kernel software-pipelined (T14 async-STAGE, 2 tiles deep):
//   - A (f32) loads go global->REGS two K-steps ahead; pack+ds_write happens
//     after the next tile's loads are issued; counted vmcnt(12/16), raw
//     s_barrier, never vmcnt(0) until the peeled tail. B via GLDS16 dbuf.
//   - This hides the ~300-900cyc A-load latency that the old per-step
//     load->pack->write->syncthreads structure exposed at every barrier
//     (proj was 135.8us, MfmaUtil 16%, nothing saturated = latency-bound).
// r12 structure kept: 5 dispatches, lss folded into attn's QK C-operand,
// fused QKV proj, attn r9 window pipeline, stats r6 form, workspace 72.5MB.
// ============================================================================

typedef unsigned short u16t;
typedef __attribute__((ext_vector_type(8))) short short8;
typedef __attribute__((ext_vector_type(4))) float floatx4;
typedef __attribute__((ext_vector_type(4))) unsigned int uintx4;

#define MFMA16(a, b, c) __builtin_amdgcn_mfma_f32_16x16x32_bf16((a), (b), (c), 0, 0, 0)
#define GLDS16(g, l)                                                        \
  __builtin_amdgcn_global_load_lds(                                         \
      (const __attribute__((address_space(1))) unsigned int*)(g),           \
      (__attribute__((address_space(3))) unsigned int*)(l), 16, 0, 0)
#define GLDS4(g, l)                                                         \
  __builtin_amdgcn_global_load_lds(                                         \
      (const __attribute__((address_space(1))) unsigned int*)(g),           \
      (__attribute__((address_space(3))) unsigned int*)(l), 4, 0, 0)

#if __has_builtin(__builtin_amdgcn_exp2f)
#define EXP2(x) __builtin_amdgcn_exp2f(x)
#else
#define EXP2(x) __expf(0.69314718f * (x))
#endif

static __device__ __forceinline__ u16t f2bf(float f) {
  union { float f; unsigned u; } v; v.f = f;
  unsigned r = v.u + 0x7FFFu + ((v.u >> 16) & 1u);  // RNE
  return (u16t)(r >> 16);
}
// Pack two f32 -> two bf16 (round-half-up) in one v_perm: hi<<16 | lo.
static __device__ __forceinline__ unsigned pack2(float hi, float lo) {
  union { float f; unsigned u; } a, b; a.f = hi; b.f = lo;
  return __builtin_amdgcn_perm(a.u + 0x8000u, b.u + 0x8000u, 0x07060302u);
}
// HW packed f32->bf16 (RNE): D = {hi16=cvt(hi), lo16=cvt(lo)} in one VALU op.
static __device__ __forceinline__ unsigned cvtpk(float lo, float hi) {
  unsigned r;
  asm("v_cvt_pk_bf16_f32 %0, %1, %2" : "=v"(r) : "v"(lo), "v"(hi));
  return r;
}

// XOR swizzle within a 64/128-elem row block: breaks 128B/256B bank period.
static __device__ __forceinline__ int swz(int row, int col) {
  return (((col >> 3) ^ (row & 7)) << 3) | (col & 7);
}

#define SEQ    2048
#define NHEAD  16
#define HDIM   64
#define DMODEL 1024

// ---------------------------------------------------------------------------
// All four W [1024][1024] f32 -> WT [n][k-swizzled] bf16 in one dispatch.
__global__ __launch_bounds__(256)
void wt_kernel(const float* __restrict__ W0, const float* __restrict__ W1,
               const float* __restrict__ W2, const float* __restrict__ W3,
               u16t* __restrict__ T0, u16t* __restrict__ T1,
               u16t* __restrict__ T2, u16t* __restrict__ T3) {
  int id = blockIdx.x * 256 + threadIdx.x;  // 2048 blocks -> 524288 ids
  int wsel = id >> 17;
  int r = id & 131071;
  int n = r & 1023;
  int k0 = (r >> 10) << 3;
  const float* W = wsel == 0 ? W0 : wsel == 1 ? W1 : wsel == 2 ? W2 : W3;
  u16t* T = wsel == 0 ? T0 : wsel == 1 ? T1 : wsel == 2 ? T2 : T3;
  const float* src = W + (size_t)k0 * 1024 + n;
  float f[8];
#pragma unroll
  for (int i = 0; i < 8; ++i) f[i] = src[(size_t)i * 1024];
  uint4 p;
  p.x = pack2(f[1], f[0]); p.y = pack2(f[3], f[2]);
  p.z = pack2(f[5], f[4]); p.w = pack2(f[7], f[6]);
  *(uint4*)&T[(size_t)n * 1024 + (k0 & ~63) + swz(n, k0 & 63)] = p;
}

// ---------------------------------------------------------------------------
// Fused QKV projection, grid (8,64,3): z selects {A, W, bias, C, epilogue}.
// A f32 is software-pipelined: global->regs 2 K-steps ahead, pack+ds_write
// deferred past the next stage issue (counted vmcnt; see header).
// z=0: Qb [b,h,s,d] swizzled, x 1/ln2.  z=1: Kb same, x1.
// z=2: Vt [b,h,d,s] swizzled with per-32 k-permutation p(k) (attn layout).
// XCD remap: raw=by*8+bx within slice; per-XCD L2 set ~4MB.
__global__ __launch_bounds__(256, 2)
void proj_kernel(const float* __restrict__ Qf, const float* __restrict__ Kf,
                 const float* __restrict__ Vf,
                 const u16t* __restrict__ WQ, const u16t* __restrict__ WK,
                 const u16t* __restrict__ WV,
                 const float* __restrict__ bq, const float* __restrict__ bk,
                 const float* __restrict__ bv,
                 u16t* __restrict__ Qb, u16t* __restrict__ Kb,
                 u16t* __restrict__ Vt) {
  constexpr int K = 1024;
  __shared__ __align__(16) u16t lA[2][128 * 64];
  __shared__ __align__(16) u16t lB[2][128 * 64];
  const int z = blockIdx.z;
  const float* Ag = z == 0 ? Qf : z == 1 ? Kf : Vf;
  const u16t* BT = z == 0 ? WQ : z == 1 ? WK : WV;
  const float* bias = z == 0 ? bq : z == 1 ? bk : bv;
  const float qsc = z == 0 ? 1.44269504f : 1.0f;
  const int tid = threadIdx.x;
  const int lane = tid & 63, w = tid >> 6;
  const int wm = w >> 1, wn = w & 1;
  const int lrow = lane & 15, lq = lane >> 4;
  const int raw = blockIdx.y * 8 + blockIdx.x;
  const int xcd = raw & 7, slot = raw >> 3;
  const int m0 = (xcd * 8 + (slot >> 3)) * 128;
  const int n0 = (slot & 7) * 128;

  // stageA: issue 8 dwordx4 A-loads for K-step t into named reg slot.
  auto stageA = [&](int t, float4 rA[8]) {
    const int kb = t << 6;
#pragma unroll
    for (int i = 0; i < 8; ++i) {
      int e = (i * 256 + tid) * 4;  // element in 128x64 tile
      int r = e >> 6, c = e & 63;
      rA[i] = *(const float4*)(Ag + (size_t)(m0 + r) * K + kb + c);
    }
  };
  // stageB: 4 GLDS16 B-loads for K-step t into lB[t&1].
  auto stageB = [&](int t) {
    const int kb = t << 6;
    u16t* dB = lB[t & 1];
#pragma unroll
    for (int i = 0; i < 4; ++i) {
      int chunk = w * 4 + i;
      int off = chunk * 1024 + lane * 16;
      int r = off >> 7, ib = off & 127;
      GLDS16(BT + (size_t)(n0 + r) * K + kb + (ib >> 1), &dB[chunk * 512]);
    }
  };
  // writeA: pack reg slot to bf16 and ds_write into dA.
  auto writeA = [&](const float4 rA[8], u16t* dA) {
#pragma unroll
    for (int i = 0; i < 8; ++i) {
      int e = (i * 256 + tid) * 4;
      int r = e >> 6, c = e & 63;
      uint2 p;
      p.x = pack2(rA[i].y, rA[i].x);
      p.y = pack2(rA[i].w, rA[i].z);
      *(uint2*)&dA[r * 64 + swz(r, c)] = p;
    }
  };

  floatx4 acc[4][4];
#pragma unroll
  for (int i = 0; i < 4; ++i)
#pragma unroll
    for (int j = 0; j < 4; ++j) acc[i][j] = {0.f, 0.f, 0.f, 0.f};

  auto compute = [&](const u16t* A_, const u16t* B_) {
#pragma unroll
    for (int kk = 0; kk < 2; ++kk) {
      short8 af[4], bfr[4];
#pragma unroll
      for (int t = 0; t < 4; ++t) {
        int ar = wm * 64 + t * 16 + lrow;
        af[t] = *(const short8*)&A_[ar * 64 + swz(ar, kk * 32 + lq * 8)];
      }
#pragma unroll
      for (int t = 0; t < 4; ++t) {
        int br = wn * 64 + t * 16 + lrow;
        bfr[t] = *(const short8*)&B_[br * 64 + swz(br, kk * 32 + lq * 8)];
      }
      __builtin_amdgcn_s_setprio(1);
#pragma unroll
      for (int i = 0; i < 4; ++i)
#pragma unroll
        for (int j = 0; j < 4; ++j)
          acc[i][j] = MFMA16(af[i], bfr[j], acc[i][j]);
      __builtin_amdgcn_s_setprio(0);
    }
  };

  float4 rEven[8], rOdd[8];
  // Prologue: stage(0), stage(1); write A(0). Issue order (FIFO):
  // A0(8) B0(4) A1(8) B1(4) -> vmcnt(16) retires A0.
  stageA(0, rEven); stageB(0);
  stageA(1, rOdd);  stageB(1);
  asm volatile("s_waitcnt vmcnt(16)" ::: "memory");
  writeA(rEven, lA[0]);

  // Steady state, t = 0..13 (parity-unrolled pairs). Invariant at body
  // entry: outstanding = B(t) A(t+1) B(t+1) = 16.
  //   vmcnt(12): B(t) done -> barrier -> compute(t) -> barrier
  //   stage(t+2) [12 more in flight] -> vmcnt(16): A(t+1) regs done
  //   -> pack+write A(t+1) into lA[(t+1)&1]
  for (int t = 0; t < 14; t += 2) {
    // body t (even): buffers 0; stage->rEven; pack rOdd
    asm volatile("s_waitcnt vmcnt(12) lgkmcnt(0)" ::: "memory");
    __builtin_amdgcn_s_barrier();
    compute(lA[0], lB[0]);
    asm volatile("s_waitcnt lgkmcnt(0)" ::: "memory");
    __builtin_amdgcn_s_barrier();
    stageA(t + 2, rEven); stageB(t + 2);
    asm volatile("s_waitcnt vmcnt(16)" ::: "memory");
    writeA(rOdd, lA[1]);
    // body t+1 (odd): buffers 1; stage->rOdd; pack rEven
    asm volatile("s_waitcnt vmcnt(12) lgkmcnt(0)" ::: "memory");
    __builtin_amdgcn_s_barrier();
    compute(lA[1], lB[1]);
    asm volatile("s_waitcnt lgkmcnt(0)" ::: "memory");
    __builtin_amdgcn_s_barrier();
    stageA(t + 3, rOdd); stageB(t + 3);
    asm volatile("s_waitcnt vmcnt(16)" ::: "memory");
    writeA(rEven, lA[0]);
  }
  // t=14: outstanding = B(14) A(15) B(15) = 16. No further staging.
  asm volatile("s_waitcnt vmcnt(12) lgkmcnt(0)" ::: "memory");
  __builtin_amdgcn_s_barrier();
  compute(lA[0], lB[0]);
  asm volatile("s_waitcnt lgkmcnt(0)" ::: "memory");
  __builtin_amdgcn_s_barrier();
  asm volatile("s_waitcnt vmcnt(4)" ::: "memory");  // A(15) regs done
  writeA(rOdd, lA[1]);
  // t=15: outstanding = B(15) = 4.
  asm volatile("s_waitcnt vmcnt(0) lgkmcnt(0)" ::: "memory");
  __builtin_amdgcn_s_barrier();
  compute(lA[1], lB[1]);

  float bvv[4];
#pragma unroll
  for (int j = 0; j < 4; ++j) bvv[j] = bias[n0 + wn * 64 + j * 16 + lrow];
  const int h = (n0 + wn * 64) >> 6;  // head: constant per wave
  u16t* Out = z == 0 ? Qb : Kb;       // z==2 handled separately
#pragma unroll
  for (int i = 0; i < 4; ++i) {
#pragma unroll
    for (int r = 0; r < 4; ++r) {
      int rg = m0 + wm * 64 + i * 16 + lq * 4 + r;  // C/D: row=(lane>>4)*4+reg
      int b = rg >> 11, s = rg & 2047;
      size_t bh = (size_t)(b * NHEAD + h);
#pragma unroll
      for (int j = 0; j < 4; ++j) {
        int cg = n0 + wn * 64 + j * 16 + lrow;
        int d = cg & 63;
        float v = acc[i][j][r] + bvv[j];
        if (z < 2) {
          Out[(bh * SEQ + s) * HDIM + swz(s, d)] = f2bf(v * qsc);
        } else {
          // per-32 column permutation p(k): position where k must sit so a
          // natural b128 read yields k = lq*4 + (e&3) + 16*(e>>2) at elem e
          int sp = (s & ~31) | (((s >> 2) & 3) << 3) | (s & 3) |
                   (((s >> 4) & 1) << 2);
          Vt[(bh * HDIM + d) * SEQ + (s & ~127) + swz(d, sp & 127)] = f2bf(v);
        }
      }
    }
  }
}

// ---------------------------------------------------------------------------
// Column-softmax stats, exp2 domain, no max (S' bounded; see header):
//   lss[k] = -3 - log2( sum_q 2^(S'[q,k]) ),  S' = Q' K^T with Q' = Q/ln2.
// (so 2^(S' + lss) = softmax_q / 8 = softmax_q / sqrt(HD))
// Grid (64,16): x = bh so all col-tiles of one bh share an XCD's L2.
__global__ __launch_bounds__(256)
void stats_kernel(const u16t* __restrict__ Qb, const u16t* __restrict__ Kb,
                  float* __restrict__ lss) {
  __shared__ __align__(16) u16t lK[128 * 64];
  __shared__ __align__(16) u16t lQ[128 * 64];
  const int tid = threadIdx.x, lane = tid & 63, w = tid >> 6;
  const int lrow = lane & 15, lq = lane >> 4;
  const int bh = blockIdx.x;
  const int c0 = blockIdx.y * 128;
  const u16t* Kbase = Kb + (size_t)bh * (SEQ * HDIM);
  const u16t* Qbase = Qb + (size_t)bh * (SEQ * HDIM);

#pragma unroll
  for (int i = 0; i < 4; ++i) {
    int chunk = w * 4 + i;
    GLDS16(Kbase + (size_t)c0 * HDIM + chunk * 512 + lane * 8, &lK[chunk * 512]);
  }

  short8 bfK[4];
  float lcur[2] = {0.f, 0.f};

  for (int q0 = 0; q0 < SEQ; q0 += 128) {
#pragma unroll
    for (int i = 0; i < 4; ++i) {
      int chunk = w * 4 + i;
      GLDS16(Qbase + (size_t)q0 * HDIM + chunk * 512 + lane * 8, &lQ[chunk * 512]);
    }
    __syncthreads();
    if (q0 == 0) {
#pragma unroll
      for (int nt = 0; nt < 2; ++nt) {
        int kr = w * 32 + nt * 16 + lrow;
        bfK[nt * 2]     = *(const short8*)&lK[kr * 64 + swz(kr, lq * 8)];
        bfK[nt * 2 + 1] = *(const short8*)&lK[kr * 64 + swz(kr, lq * 8 + 32)];
      }
    }
#pragma unroll
    for (int mt = 0; mt < 8; ++mt) {
      int qr = mt * 16 + lrow;
      short8 af0 = *(const short8*)&lQ[qr * 64 + swz(qr, lq * 8)];
      short8 af1 = *(const short8*)&lQ[qr * 64 + swz(qr, lq * 8 + 32)];
#pragma unroll
      for (int nt = 0; nt < 2; ++nt) {
        floatx4 a = {0.f, 0.f, 0.f, 0.f};
        a = MFMA16(af0, bfK[nt * 2], a);
        a = MFMA16(af1, bfK[nt * 2 + 1], a);
        lcur[nt] += EXP2(a[0]) + EXP2(a[1]) + EXP2(a[2]) + EXP2(a[3]);
      }
    }
    __syncthreads();
  }
  // lanes {l, l^16, l^32, l^48} hold disjoint q-subsets of the same column
#pragma unroll
  for (int t = 0; t < 2; ++t) {
    float ll = lcur[t];
    ll += __shfl_xor(ll, 16);
    ll += __shfl_xor(ll, 32);
    lcur[t] = ll;
  }
  if (lane < 16) {
#pragma unroll
    for (int t = 0; t < 2; ++t) {
      int col = c0 + w * 32 + t * 16 + lane;
      lss[(size_t)bh * SEQ + col] = -3.0f - __log2f(lcur[t]);
    }
  }
}

// ---------------------------------------------------------------------------
// attn: per (b,h, 256-q tile): loop 128-k tiles (LDS double-buffered), each
// split into 4 32-k windows, software-pipelined WITHIN the wave (r9 form):
//   prologue: QK(win 0) -> exp/pack; per window: QK(kw+1) before PV(kw),
//   exp/pack(kw+1) after PV-issue.
// QK MFMA C-operand is initialized with lss[k] (k-only -> broadcast
// ds_read from a tiny staged lss tile), so P~ = 2^(S'+lss) is the
// normalized softmax/8 directly; V is unscaled.
// Counted vmcnt(10) (10 loads/stage: 4 K + 4 V + 2 lss), raw s_barrier,
// never vmcnt(0) mid-loop. LDS 65KB -> 2 blocks/CU.
__global__ __launch_bounds__(256, 2)
void attn_kernel(const u16t* __restrict__ Qb, const u16t* __restrict__ Kb,
                 const u16t* __restrict__ Vt, const float* __restrict__ Lb,
                 u16t* __restrict__ Hout) {
  __shared__ __align__(16) u16t sK[2][8192];   // [buf][128k x 64d]
  __shared__ __align__(16) u16t sV[2][8192];   // [buf][64d x 128k]
  __shared__ __align__(16) float sL[2][128];   // [buf][128k] lss tile
  const int tid = threadIdx.x, lane = tid & 63, w = tid >> 6;
  const int lrow = lane & 15, lq = lane >> 4;
  const int bh = blockIdx.x, q0 = blockIdx.y * 256;
  const size_t hb = (size_t)bh * (SEQ * HDIM);
  const float* Lg = Lb + (size_t)bh * SEQ;

  auto stage = [&](int t) {
    u16t* dK = sK[t & 1];
    u16t* dV = sV[t & 1];
    float* dL = sL[t & 1];
    const int k0 = t << 7;
#pragma unroll
    for (int i = 0; i < 4; ++i) {
      int chunk = w * 4 + i;
      GLDS16(Kb + hb + (size_t)k0 * HDIM + chunk * 512 + lane * 8, &dK[chunk * 512]);
    }
#pragma unroll
    for (int i = 0; i < 4; ++i) {
      int chunk = w * 4 + i;
      int off = chunk * 1024 + lane * 16;
      int d = off >> 8, ib = off & 255;
      GLDS16(Vt + hb + ((size_t)d << 11) + k0 + (ib >> 1), &dV[chunk * 512]);
    }
    GLDS4(Lg + k0 + lane, &dL[0]);        // lanes -> dL[0..63]
    GLDS4(Lg + k0 + 64 + lane, &dL[64]);  // lanes -> dL[64..127]
  };
  auto loadK = [&](short8 dst[2][2], const u16t* K_, int kw) {
#pragma unroll
    for (int t = 0; t < 2; ++t) {
      int kr = (kw * 2 + t) * 16 + lrow;
      dst[t][0] = *(const short8*)&K_[kr * 64 + swz(kr, lq * 8)];
      dst[t][1] = *(const short8*)&K_[kr * 64 + swz(kr, lq * 8 + 32)];
    }
  };
  auto loadV = [&](short8 dst[4], const u16t* V_, int kw) {
#pragma unroll
    for (int dt = 0; dt < 4; ++dt) {
      int vr = dt * 16 + lrow;
      dst[dt] = *(const short8*)&V_[vr * 128 + swz(vr, kw * 32 + lq * 8)];
    }
  };

  // Stage the 32KB Q tile through sK (both buffers), lift 8 frags to regs.
  u16t* qs = (u16t*)sK;
#pragma unroll
  for (int i = 0; i < 8; ++i) {
    int chunk = w * 8 + i;
    GLDS16(Qb + hb + (size_t)q0 * HDIM + chunk * 512 + lane * 8, &qs[chunk * 512]);
  }
  __syncthreads();
  short8 bq[4][2];
#pragma unroll
  for (int j = 0; j < 4; ++j) {
    int qr = w * 64 + j * 16 + lrow;
    bq[j][0] = *(const short8*)&qs[qr * 64 + swz(qr, lq * 8)];
    bq[j][1] = *(const short8*)&qs[qr * 64 + swz(qr, lq * 8 + 32)];
  }
  __syncthreads();  // everyone has Q frags before stage(0) overwrites sK

  // QK issue: 16 MFMA for one 32-k window; C-in = lss broadcast (cA, cB)
  auto qk = [&](const short8 ak[2][2], floatx4 s[4][2], floatx4 cA, floatx4 cB) {
    __builtin_amdgcn_s_setprio(1);
#pragma unroll
    for (int j = 0; j < 4; ++j) {
      floatx4 a = cA, b = cB;
      a = MFMA16(ak[0][0], bq[j][0], a);
      a = MFMA16(ak[0][1], bq[j][1], a);
      b = MFMA16(ak[1][0], bq[j][0], b);
      b = MFMA16(ak[1][1], bq[j][1], b);
      s[j][0] = a; s[j][1] = b;
    }
    __builtin_amdgcn_s_setprio(0);
  };
  // exp/pack: S -> P~ bf16 PV A-frags
  auto ep = [&](const floatx4 s[4][2], short8 pa[4]) {
#pragma unroll
    for (int j = 0; j < 4; ++j) {
      uintx4 pw;
      pw[0] = cvtpk(EXP2(s[j][0][0]), EXP2(s[j][0][1]));
      pw[1] = cvtpk(EXP2(s[j][0][2]), EXP2(s[j][0][3]));
      pw[2] = cvtpk(EXP2(s[j][1][0]), EXP2(s[j][1][1]));
      pw[3] = cvtpk(EXP2(s[j][1][2]), EXP2(s[j][1][3]));
      pa[j] = __builtin_bit_cast(short8, pw);
    }
  };

  floatx4 ao[4][4];
#pragma unroll
  for (int j = 0; j < 4; ++j)
#pragma unroll
    for (int t = 0; t < 4; ++t) ao[j][t] = {0.f, 0.f, 0.f, 0.f};

  stage(0);
  stage(1);  // 20 loads in flight

#pragma unroll 2
  for (int kt = 0; kt < 16; ++kt) {
    if (kt < 15) asm volatile("s_waitcnt vmcnt(10)" ::: "memory");  // kt done
    else         asm volatile("s_waitcnt vmcnt(0)" ::: "memory");
    __builtin_amdgcn_s_barrier();
    const u16t* K_ = sK[kt & 1];
    const u16t* V_ = sV[kt & 1];
    const float* L_ = sL[kt & 1];

    // prologue: QK + exp/pack for window 0
    short8 ak0[2][2];
    loadK(ak0, K_, 0);
    floatx4 cA = *(const floatx4*)&L_[lq * 4];
    floatx4 cB = *(const floatx4*)&L_[16 + lq * 4];
    floatx4 s0[4][2];
    qk(ak0, s0, cA, cB);
    short8 pa[4];
    ep(s0, pa);

#pragma unroll
    for (int kw = 0; kw < 4; ++kw) {
      short8 bv[4];
      loadV(bv, V_, kw);
      short8 akN[2][2];
      floatx4 sN[4][2];
      if (kw < 3) {
        loadK(akN, K_, kw + 1);
        floatx4 cAn = *(const floatx4*)&L_[(kw + 1) * 32 + lq * 4];
        floatx4 cBn = *(const floatx4*)&L_[(kw + 1) * 32 + 16 + lq * 4];
        qk(akN, sN, cAn, cBn);     // next window's QK issued BEFORE this PV
      }
      __builtin_amdgcn_s_setprio(1);
#pragma unroll
      for (int dt = 0; dt < 4; ++dt)
#pragma unroll
        for (int j = 0; j < 4; ++j)
          ao[j][dt] = MFMA16(pa[j], bv[dt], ao[j][dt]);
      __builtin_amdgcn_s_setprio(0);
      if (kw < 3) {
        short8 paN[4];
        ep(sN, paN);               // exps overlap the PV drain
#pragma unroll
        for (int j = 0; j < 4; ++j) pa[j] = paN[j];
      }
    }

    asm volatile("s_waitcnt lgkmcnt(0)" ::: "memory");
    __builtin_amdgcn_s_barrier();  // all waves done reading buf kt&1
    if (kt < 14) stage(kt + 2);    // refill the buffer just consumed
  }

  // Hout[b][q][h*64+d], swizzled (key q&7) for outproj's GLDS16 staging
  const int b = bh >> 4, h = bh & 15;
#pragma unroll
  for (int j = 0; j < 4; ++j)
#pragma unroll
    for (int dt = 0; dt < 4; ++dt) {
      int d = dt * 16 + lrow;
#pragma unroll
      for (int r = 0; r < 4; ++r) {
        int q = q0 + w * 64 + j * 16 + lq * 4 + r;
        Hout[((size_t)b * SEQ + q) * DMODEL + h * HDIM + swz(q, d)] = f2bf(ao[j][dt][r]);
      }
    }
}

// ---------------------------------------------------------------------------
// Out-projection: C[8192,1024] f32 = Hout[8192,1024](bf16 swz) * WO^T + bias.
// Proven single-buffer GLDS16 loop.
__global__ __launch_bounds__(256)
void outproj_kernel(const u16t* __restrict__ Ag, const u16t* __restrict__ BT,
                    const float* __restrict__ bias, float* __restrict__ Cp) {
  constexpr int K = 1024;
  __shared__ __align__(16) u16t lA[128 * 64];
  __shared__ __align__(16) u16t lB[128 * 64];
  const int tid = threadIdx.x;
  const int lane = tid & 63, w = tid >> 6;
  const int wm = w >> 1, wn = w & 1;
  const int lrow = lane & 15, lq = lane >> 4;
  const int raw = blockIdx.y * 8 + blockIdx.x;
  const int xcd = raw & 7, slot = raw >> 3;
  const int m0 = (xcd * 8 + (slot >> 3)) * 128;
  const int n0 = (slot & 7) * 128;

  floatx4 acc[4][4];
#pragma unroll
  for (int i = 0; i < 4; ++i)
#pragma unroll
    for (int j = 0; j < 4; ++j) acc[i][j] = {0.f, 0.f, 0.f, 0.f};

  for (int kb = 0; kb < K; kb += 64) {
#pragma unroll
    for (int i = 0; i < 4; ++i) {
      int chunk = w * 4 + i;
      int off = chunk * 1024 + lane * 16;
      int r = off >> 7, ib = off & 127;
      GLDS16(Ag + (size_t)(m0 + r) * K + kb + (ib >> 1), &lA[chunk * 512]);
      GLDS16(BT + (size_t)(n0 + r) * K + kb + (ib >> 1), &lB[chunk * 512]);
    }
    __syncthreads();
#pragma unroll
    for (int kk = 0; kk < 2; ++kk) {
      short8 af[4], bfr[4];
#pragma unroll
      for (int t = 0; t < 4; ++t) {
        int ar = wm * 64 + t * 16 + lrow;
        af[t] = *(const short8*)&lA[ar * 64 + swz(ar, kk * 32 + lq * 8)];
      }
#pragma unroll
      for (int t = 0; t < 4; ++t) {
        int br = wn * 64 + t * 16 + lrow;
        bfr[t] = *(const short8*)&lB[br * 64 + swz(br, kk * 32 + lq * 8)];
      }
#pragma unroll
      for (int i = 0; i < 4; ++i)
#pragma unroll
        for (int j = 0; j < 4; ++j)
          acc[i][j] = MFMA16(af[i], bfr[j], acc[i][j]);
    }
    __syncthreads();
  }

  float bvv[4];
#pragma unroll
  for (int j = 0; j < 4; ++j) bvv[j] = bias[n0 + wn * 64 + j * 16 + lrow];
#pragma unroll
  for (int i = 0; i < 4; ++i) {
#pragma unroll
    for (int r = 0; r < 4; ++r) {
      int rg = m0 + wm * 64 + i * 16 + lq * 4 + r;
#pragma unroll
      for (int j = 0; j < 4; ++j) {
        int cg = n0 + wn * 64 + j * 16 + lrow;
        Cp[(size_t)rg * 1024 + cg] = acc[i][j][r] + bvv[j];
      }
    }
  }
}

// ---------------------------------------------------------------------------
extern "C" void kernel_launch(void* const* d_in, const int* in_sizes, int n_in,
                              void* d_out, int out_size, void* d_ws, size_t ws_size,
                              hipStream_t stream) {
  (void)in_sizes; (void)n_in; (void)out_size; (void)ws_size;
  const float* queries = (const float*)d_in[0];
  const float* keys    = (const float*)d_in[1];
  const float* values  = (const float*)d_in[2];
  const float* Wq = (const float*)d_in[3];
  const float* bq = (const float*)d_in[4];
  const float* Wk = (const float*)d_in[5];
  const float* bk = (const float*)d_in[6];
  const float* Wv = (const float*)d_in[7];
  const float* bv = (const float*)d_in[8];
  const float* Wo = (const float*)d_in[9];
  const float* bo = (const float*)d_in[10];

  char* ws = (char*)d_ws;
  const size_t MB = 1024 * 1024;
  u16t* Qb   = (u16t*)(ws + 0 * MB);    // [b,h,s,d] bf16 swizzled (x 1/ln2)
  u16t* Kb   = (u16t*)(ws + 16 * MB);   // [b,h,s,d] bf16 swizzled
  u16t* Hout = (u16t*)(ws + 32 * MB);   // [b,s,dm] bf16 swizzled
  u16t* Vt   = (u16t*)(ws + 48 * MB);   // [b,h,d,s] bf16 swz+perm (unscaled)
  u16t* wqt  = (u16t*)(ws + 64 * MB);   // [n][k] bf16 swizzled, 2MB each
  u16t* wkt  = (u16t*)(ws + 66 * MB);
  u16t* wvt  = (u16t*)(ws + 68 * MB);
  u16t* wot  = (u16t*)(ws + 70 * MB);
  float* lss = (float*)(ws + 72 * MB);  // [bh][s]  -3 - log2(sum 2^S')

  wt_kernel<<<2048, 256, 0, stream>>>(Wq, Wk, Wv, Wo, wqt, wkt, wvt, wot);

  proj_kernel<<<dim3(8, 64, 3), 256, 0, stream>>>(
      queries, keys, values, wqt, wkt, wvt, bq, bk, bv, Qb, Kb, Vt);

  stats_kernel<<<dim3(64, 16), 256, 0, stream>>>(Qb, Kb, lss);

  attn_kernel<<<dim3(64, 8), 256, 0, stream>>>(Qb, Kb, Vt, lss, Hout);

  outproj_kernel<<<dim3(8, 64), 256, 0, stream>>>(Hout, wot, bo, (float*)d_out);
}